// Round 2
// baseline (470.134 us; speedup 1.0000x reference)
//
#include <hip/hip_runtime.h>
#include <hip/hip_bf16.h>

#define NN 2048

// ---------------- GEMM: C[N,M](fp32) = A[N,K] * B[K,M](fp32), ROWS rows/block ----------------
template<int K, int M, int ROWS>
__global__ __launch_bounds__(M) void gemm_rows(const float* __restrict__ A,
                                               const float* __restrict__ B,
                                               float* __restrict__ C) {
    __shared__ float xs[ROWS][K];
    const int i0 = blockIdx.x * ROWS;
    const int j = threadIdx.x;
    for (int t = threadIdx.x; t < ROWS * K; t += M)
        xs[t / K][t % K] = A[(size_t)(i0 + t / K) * K + (t % K)];
    __syncthreads();
    float acc[ROWS];
#pragma unroll
    for (int r = 0; r < ROWS; ++r) acc[r] = 0.f;
#pragma unroll 4
    for (int k = 0; k < K; ++k) {
        float b = B[(size_t)k * M + j];
#pragma unroll
        for (int r = 0; r < ROWS; ++r) acc[r] += xs[r][k] * b;
    }
#pragma unroll
    for (int r = 0; r < ROWS; ++r) C[(size_t)(i0 + r) * M + j] = acc[r];
}

// ---------------- el[i,h] = g[i,h,:].a_l ; er[i,h] = g[i,h,:].a_r ----------------
template<int NH, int F>
__global__ void elr_kernel(const float* __restrict__ g,
                           const float* __restrict__ al,
                           const float* __restrict__ ar,
                           float* __restrict__ el, float* __restrict__ er) {
    int t = blockIdx.x * blockDim.x + threadIdx.x; // t = i*NH + h
    if (t >= NN * NH) return;
    const float* gp = g + (size_t)t * F; // (i*NH+h)*F
    float sl = 0.f, sr = 0.f;
#pragma unroll 8
    for (int f = 0; f < F; ++f) {
        float v = gp[f];
        sl += v * al[f];
        sr += v * ar[f];
    }
    el[t] = sl;
    er[t] = sr;
}

// ---------------- masked softmax attention + aggregation, RI rows per block ----------------
// thread tid = h*F + f. Pass 1: row max per head. Pass 2: tiled p staging + aggregation.
template<int NH, int F, int TJ, int RI, bool ELU_OUT>
__global__ __launch_bounds__(NH * F) void attn_kernel(
        const float* __restrict__ g, const float* __restrict__ el,
        const float* __restrict__ er, const int* __restrict__ adj,
        float* __restrict__ out) {
    constexpr int BLOCK = NH * F;
    constexpr int WAVES = BLOCK / 64;
    const int i0 = blockIdx.x * RI;
    const int tid = threadIdx.x;
    const int h = tid / F;

    __shared__ float elsh[RI][NH];
    __shared__ float msh[RI][NH];
    __shared__ float wred[WAVES][RI][NH];
    __shared__ float pl[RI][TJ * NH];

    if (tid < RI * NH) elsh[tid / NH][tid % NH] = el[(size_t)i0 * NH + tid];
    __syncthreads();

    // ---- pass 1: per-(row,head) max over unmasked j ----
    float mx[RI][NH];
#pragma unroll
    for (int r = 0; r < RI; ++r)
#pragma unroll
        for (int hh = 0; hh < NH; ++hh) mx[r][hh] = -1e30f;

    for (int j = tid; j < NN; j += BLOCK) {
        float erj[NH];
#pragma unroll
        for (int hh = 0; hh < NH; ++hh) erj[hh] = er[(size_t)j * NH + hh];
#pragma unroll
        for (int r = 0; r < RI; ++r) {
            int a = adj[(size_t)(i0 + r) * NN + j];
            if (a) {
#pragma unroll
                for (int hh = 0; hh < NH; ++hh) {
                    float s = elsh[r][hh] + erj[hh];
                    s = s > 0.f ? s : 0.2f * s;
                    mx[r][hh] = fmaxf(mx[r][hh], s);
                }
            }
        }
    }
#pragma unroll
    for (int r = 0; r < RI; ++r)
#pragma unroll
        for (int hh = 0; hh < NH; ++hh)
            for (int off = 32; off > 0; off >>= 1)
                mx[r][hh] = fmaxf(mx[r][hh], __shfl_down(mx[r][hh], off));
    const int lane = tid & 63, wave = tid >> 6;
    if (lane == 0) {
#pragma unroll
        for (int r = 0; r < RI; ++r)
#pragma unroll
            for (int hh = 0; hh < NH; ++hh) wred[wave][r][hh] = mx[r][hh];
    }
    __syncthreads();
    if (tid < RI * NH) {
        int r = tid / NH, hh = tid % NH;
        float m = wred[0][r][hh];
#pragma unroll
        for (int w = 1; w < WAVES; ++w) m = fmaxf(m, wred[w][r][hh]);
        msh[r][hh] = m;
    }
    __syncthreads();

    // ---- pass 2: tiled p + aggregation ----
    float acc[RI], psum[RI];
#pragma unroll
    for (int r = 0; r < RI; ++r) { acc[r] = 0.f; psum[r] = 0.f; }

    for (int j0 = 0; j0 < NN; j0 += TJ) {
#pragma unroll
        for (int r2 = 0; r2 < 2; ++r2) {
            int v = tid * 2 + r2;            // v in [0, TJ*NH)
            int jj = v / NH, hh = v % NH;
            int j = j0 + jj;
            float erv = er[(size_t)j * NH + hh];
#pragma unroll
            for (int r = 0; r < RI; ++r) {
                int a = adj[(size_t)(i0 + r) * NN + j];
                float p = 0.f;
                if (a) {
                    float s = elsh[r][hh] + erv;
                    s = s > 0.f ? s : 0.2f * s;
                    p = __expf(s - msh[r][hh]);
                }
                pl[r][v] = p;
            }
        }
        __syncthreads();
#pragma unroll 4
        for (int jj = 0; jj < TJ; ++jj) {
            float gv = g[(size_t)(j0 + jj) * BLOCK + tid];
#pragma unroll
            for (int r = 0; r < RI; ++r) {
                float p = pl[r][jj * NH + h];
                psum[r] += p;
                acc[r] += p * gv;
            }
        }
        __syncthreads();
    }

#pragma unroll
    for (int r = 0; r < RI; ++r) {
        float o = acc[r] / psum[r];
        if constexpr (ELU_OUT) o = o > 0.f ? o : (__expf(o) - 1.f);
        out[(size_t)(i0 + r) * BLOCK + tid] = o;
    }
}

extern "C" void kernel_launch(void* const* d_in, const int* in_sizes, int n_in,
                              void* d_out, int out_size, void* d_ws, size_t ws_size,
                              hipStream_t stream) {
    const float* x   = (const float*)d_in[0];
    const float* W1  = (const float*)d_in[1];
    const float* a1l = (const float*)d_in[2];
    const float* a1r = (const float*)d_in[3];
    const float* W2  = (const float*)d_in[4];
    const float* a2l = (const float*)d_in[5];
    const float* a2r = (const float*)d_in[6];
    const int* adj = (const int*)d_in[7];

    float* ws  = (float*)d_ws;
    float* g1  = ws;                    // 2048*256
    float* el1 = g1 + (size_t)NN * 256; // 2048*8
    float* er1 = el1 + (size_t)NN * 8;  // 2048*8
    float* hb  = er1 + (size_t)NN * 8;  // 2048*256 (post-ELU layer1 output, fp32)
    float* g2  = hb + (size_t)NN * 256; // 2048*128
    float* el2 = g2 + (size_t)NN * 128; // 2048
    float* er2 = el2 + (size_t)NN;      // 2048

    // Layer 1: g1 = x @ W1
    gemm_rows<512, 256, 4><<<NN / 4, 256, 0, stream>>>(x, W1, g1);
    elr_kernel<8, 32><<<(NN * 8) / 256, 256, 0, stream>>>(g1, a1l, a1r, el1, er1);
    attn_kernel<8, 32, 64, 4, true><<<NN / 4, 256, 0, stream>>>(g1, el1, er1, adj, hb);

    // Layer 2: g2 = hb @ W2
    gemm_rows<256, 128, 4><<<NN / 4, 128, 0, stream>>>(hb, W2, g2);
    elr_kernel<1, 128><<<(NN * 1) / 256, 256, 0, stream>>>(g2, a2l, a2r, el2, er2);
    attn_kernel<1, 128, 256, 4, false><<<NN / 4, 128, 0, stream>>>(
        g2, el2, er2, adj, (float*)d_out);
}

// Round 3
// 270.765 us; speedup vs baseline: 1.7363x; 1.7363x over previous
//
#include <hip/hip_runtime.h>
#include <hip/hip_bf16.h>

#define NN 2048

// monotone float<->uint map for atomicMax on floats (handles negatives)
__device__ __forceinline__ unsigned fmono(float x) {
    unsigned b = __float_as_uint(x);
    return (b & 0x80000000u) ? ~b : (b | 0x80000000u);
}
__device__ __forceinline__ float fmono_inv(unsigned u) {
    return (u & 0x80000000u) ? __uint_as_float(u ^ 0x80000000u) : __uint_as_float(~u);
}

// ---------------- GEMM: C[N,M] = A[N,K] * B[K,M], fp32, K split across SL slices ----------------
template<int K, int M, int ROWS, int SL>
__global__ __launch_bounds__(M * SL) void gemm_ksplit(const float* __restrict__ A,
                                                      const float* __restrict__ B,
                                                      float* __restrict__ C) {
    static_assert(ROWS == 4, "float4 path assumes ROWS==4");
    constexpr int TOT = M * SL;
    __shared__ float xs[K][ROWS];
    __shared__ float acc_sh[SL - 1][ROWS][M];
    const int i0 = blockIdx.x * ROWS;
    const int tid = threadIdx.x;
    const int s = tid / M, j = tid % M;

    for (int q = tid; q < ROWS * K / 4; q += TOT) {
        int r = (q * 4) / K, k0 = (q * 4) % K;
        float4 av = *(const float4*)&A[(size_t)(i0 + r) * K + k0];
        xs[k0][r] = av.x; xs[k0 + 1][r] = av.y; xs[k0 + 2][r] = av.z; xs[k0 + 3][r] = av.w;
    }
    __syncthreads();

    float acc[ROWS] = {0.f, 0.f, 0.f, 0.f};
    const int kb = s * (K / SL), ke = kb + K / SL;
#pragma unroll 4
    for (int k = kb; k < ke; ++k) {
        float b = B[(size_t)k * M + j];
        float4 xv = *(const float4*)&xs[k][0];
        acc[0] += xv.x * b; acc[1] += xv.y * b; acc[2] += xv.z * b; acc[3] += xv.w * b;
    }
    if (s > 0) {
#pragma unroll
        for (int r = 0; r < ROWS; ++r) acc_sh[s - 1][r][j] = acc[r];
    }
    __syncthreads();
    if (s == 0) {
#pragma unroll
        for (int r = 0; r < ROWS; ++r) {
            float o = acc[r];
#pragma unroll
            for (int ss = 0; ss < SL - 1; ++ss) o += acc_sh[ss][r][j];
            C[(size_t)(i0 + r) * M + j] = o;
        }
    }
}

// ---------------- el/er + global er-max per head (via monotone-uint atomicMax) ----------------
template<int NH, int F>
__global__ void elr_kernel(const float* __restrict__ g,
                           const float* __restrict__ al,
                           const float* __restrict__ ar,
                           float* __restrict__ el, float* __restrict__ er,
                           unsigned* __restrict__ ermax_u) {
    int t = blockIdx.x * blockDim.x + threadIdx.x; // t = i*NH + h
    const float4* gp = (const float4*)(g + (size_t)t * F);
    const float4* alp = (const float4*)al;
    const float4* arp = (const float4*)ar;
    float sl = 0.f, sr = 0.f;
#pragma unroll
    for (int q = 0; q < F / 4; ++q) {
        float4 v = gp[q], A = alp[q], R = arp[q];
        sl += v.x * A.x + v.y * A.y + v.z * A.z + v.w * A.w;
        sr += v.x * R.x + v.y * R.y + v.z * R.z + v.w * R.w;
    }
    el[t] = sl;
    er[t] = sr;

    unsigned m = fmono(sr);
    const int lane = threadIdx.x & 63;
    if constexpr (NH == 8) {
#pragma unroll
        for (int off = 8; off <= 32; off <<= 1) {
            unsigned o = (unsigned)__shfl_xor((int)m, off);
            m = m > o ? m : o;
        }
        if (lane < 8) atomicMax(&ermax_u[lane], m); // lane<8 -> h = lane (256%8==0)
    } else {
#pragma unroll
        for (int off = 1; off <= 32; off <<= 1) {
            unsigned o = (unsigned)__shfl_xor((int)m, off);
            m = m > o ? m : o;
        }
        if (lane == 0) atomicMax(&ermax_u[0], m);
    }
}

// ---------------- masked softmax attention + aggregation ----------------
// RI rows/block, SL j-slices of JS=NN/SL each. No max pass: m = lrelu(el + ermax).
template<int NH, int F, int SL, int TJ, int RI, bool ELU_OUT>
__global__ __launch_bounds__(NH * F * SL, 8) void attn_kernel(
        const float* __restrict__ g, const float* __restrict__ el,
        const float* __restrict__ er, const unsigned* __restrict__ ermax_u,
        const int* __restrict__ adj, float* __restrict__ out) {
    constexpr int BT = NH * F;        // threads per slice == feature width
    constexpr int TOT = BT * SL;
    constexpr int JS = NN / SL;
    constexpr int TJP = (NH > 1) ? (TJ + 4) : TJ; // pad jj-stride to break staging conflicts

    const int i0 = blockIdx.x * RI;
    const int tid = threadIdx.x;
    const int s = tid / BT;
    const int t = tid % BT;
    const int h = t / F;

    __shared__ float elsh[RI][NH];
    __shared__ float msh[RI][NH];
    __shared__ float pl[SL][RI][NH][TJP];
    __shared__ float acc_sh[SL][RI][BT];
    __shared__ float psum_sh[SL][RI][NH];

    if (tid < RI * NH) {
        int r = tid / NH, hh = tid % NH;
        float e = el[(size_t)i0 * NH + tid];
        elsh[r][hh] = e;
        float m = e + fmono_inv(ermax_u[hh]);
        msh[r][hh] = m > 0.f ? m : 0.2f * m;
    }
    __syncthreads();

    float acc[RI], psum[RI];
#pragma unroll
    for (int r = 0; r < RI; ++r) { acc[r] = 0.f; psum[r] = 0.f; }

    const int jbase = s * JS;
    for (int jt = 0; jt < JS; jt += TJ) {
        const int j0 = jbase + jt;
        // ---- stage p tile (transposed: [r][h][jj]) ----
        for (int v = t; v < TJ * NH; v += BT) {
            int jj = v / NH, hh = v % NH;
            int j = j0 + jj;
            float erv = er[(size_t)j * NH + hh];
#pragma unroll
            for (int r = 0; r < RI; ++r) {
                int a = adj[(size_t)(i0 + r) * NN + j];
                float sc = elsh[r][hh] + erv;
                sc = sc > 0.f ? sc : 0.2f * sc;
                float p = a ? __expf(sc - msh[r][hh]) : 0.f;
                pl[s][r][hh][jj] = p;
            }
        }
        __syncthreads();
        // ---- aggregate ----
#pragma unroll 2
        for (int jj4 = 0; jj4 < TJ; jj4 += 4) {
            float gv[4];
#pragma unroll
            for (int k2 = 0; k2 < 4; ++k2)
                gv[k2] = g[(size_t)(j0 + jj4 + k2) * BT + t];
#pragma unroll
            for (int r = 0; r < RI; ++r) {
                const float4 p4 = *(const float4*)&pl[s][r][h][jj4];
                psum[r] += (p4.x + p4.y) + (p4.z + p4.w);
                acc[r] += p4.x * gv[0];
                acc[r] += p4.y * gv[1];
                acc[r] += p4.z * gv[2];
                acc[r] += p4.w * gv[3];
            }
        }
        __syncthreads();
    }

    // ---- write partials & combine across slices ----
#pragma unroll
    for (int r = 0; r < RI; ++r) acc_sh[s][r][t] = acc[r];
    if (t % F == 0) {
#pragma unroll
        for (int r = 0; r < RI; ++r) psum_sh[s][r][h] = psum[r];
    }
    __syncthreads();

    for (int u = tid; u < RI * BT; u += TOT) {
        int r = u / BT, tt = u % BT, hh = tt / F;
        float o = 0.f, ps = 0.f;
#pragma unroll
        for (int ss = 0; ss < SL; ++ss) {
            o += acc_sh[ss][r][tt];
            ps += psum_sh[ss][r][hh];
        }
        o /= ps;
        if constexpr (ELU_OUT) o = o > 0.f ? o : (__expf(o) - 1.f);
        out[(size_t)(i0 + r) * BT + tt] = o;
    }
}

extern "C" void kernel_launch(void* const* d_in, const int* in_sizes, int n_in,
                              void* d_out, int out_size, void* d_ws, size_t ws_size,
                              hipStream_t stream) {
    const float* x   = (const float*)d_in[0];
    const float* W1  = (const float*)d_in[1];
    const float* a1l = (const float*)d_in[2];
    const float* a1r = (const float*)d_in[3];
    const float* W2  = (const float*)d_in[4];
    const float* a2l = (const float*)d_in[5];
    const float* a2r = (const float*)d_in[6];
    const int* adj = (const int*)d_in[7];

    float* ws  = (float*)d_ws;
    float* g1  = ws;                       // 2048*256
    float* el1 = g1 + (size_t)NN * 256;    // 2048*8
    float* er1 = el1 + (size_t)NN * 8;     // 2048*8
    float* hb  = er1 + (size_t)NN * 8;     // 2048*256
    float* g2  = hb + (size_t)NN * 256;    // 2048*128
    float* el2 = g2 + (size_t)NN * 128;    // 2048
    float* er2 = el2 + (size_t)NN;         // 2048
    unsigned* ermax1 = (unsigned*)(er2 + (size_t)NN); // 8
    unsigned* ermax2 = ermax1 + 8;                    // 1

    hipMemsetAsync(ermax1, 0, 9 * sizeof(unsigned), stream);

    // Layer 1
    gemm_ksplit<512, 256, 4, 4><<<NN / 4, 1024, 0, stream>>>(x, W1, g1);
    elr_kernel<8, 32><<<(NN * 8) / 256, 256, 0, stream>>>(g1, a1l, a1r, el1, er1, ermax1);
    attn_kernel<8, 32, 4, 64, 4, true><<<NN / 4, 1024, 0, stream>>>(g1, el1, er1, ermax1, adj, hb);

    // Layer 2
    gemm_ksplit<256, 128, 4, 8><<<NN / 4, 1024, 0, stream>>>(hb, W2, g2);
    elr_kernel<1, 128><<<NN / 256, 256, 0, stream>>>(g2, a2l, a2r, el2, er2, ermax2);
    attn_kernel<1, 128, 8, 128, 4, false><<<NN / 4, 1024, 0, stream>>>(g2, el2, er2, ermax2, adj, (float*)d_out);
}

// Round 4
// 180.023 us; speedup vs baseline: 2.6115x; 1.5041x over previous
//
#include <hip/hip_runtime.h>
#include <hip/hip_bf16.h>

#define NN 2048

typedef __attribute__((ext_vector_type(8))) short short8;
typedef __attribute__((ext_vector_type(4))) float f32x4;

// monotone float<->uint map for atomicMax on floats (handles negatives)
__device__ __forceinline__ unsigned fmono(float x) {
    unsigned b = __float_as_uint(x);
    return (b & 0x80000000u) ? ~b : (b | 0x80000000u);
}
__device__ __forceinline__ float fmono_inv(unsigned u) {
    return (u & 0x80000000u) ? __uint_as_float(u ^ 0x80000000u) : __uint_as_float(~u);
}
__device__ __forceinline__ float lrelu(float s) { return s > 0.f ? s : 0.2f * s; }
// fp32 -> bf16 bits, round-to-nearest-even (p >= 0, no NaN possible here)
__device__ __forceinline__ unsigned bfb(float x) {
    unsigned u = __float_as_uint(x);
    return (u + 0x7FFFu + ((u >> 16) & 1u)) >> 16;
}

// ---------------- GEMM: C[N,M] = A[N,K] * B[K,M], fp32; also writes GT[f][i] = bf16(C) ----------------
template<int K, int M, int ROWS, int SL>
__global__ __launch_bounds__(M * SL) void gemm_ksplit(const float* __restrict__ A,
                                                      const float* __restrict__ B,
                                                      float* __restrict__ C,
                                                      unsigned short* __restrict__ GT) {
    static_assert(ROWS == 4, "float4 path assumes ROWS==4");
    constexpr int TOT = M * SL;
    __shared__ float xs[K][ROWS];
    __shared__ float acc_sh[SL - 1][ROWS][M];
    const int i0 = blockIdx.x * ROWS;
    const int tid = threadIdx.x;
    const int s = tid / M, j = tid % M;

    for (int q = tid; q < ROWS * K / 4; q += TOT) {
        int r = (q * 4) / K, k0 = (q * 4) % K;
        float4 av = *(const float4*)&A[(size_t)(i0 + r) * K + k0];
        xs[k0][r] = av.x; xs[k0 + 1][r] = av.y; xs[k0 + 2][r] = av.z; xs[k0 + 3][r] = av.w;
    }
    __syncthreads();

    float acc[ROWS] = {0.f, 0.f, 0.f, 0.f};
    const int kb = s * (K / SL), ke = kb + K / SL;
#pragma unroll 4
    for (int k = kb; k < ke; ++k) {
        float b = B[(size_t)k * M + j];
        float4 xv = *(const float4*)&xs[k][0];
        acc[0] += xv.x * b; acc[1] += xv.y * b; acc[2] += xv.z * b; acc[3] += xv.w * b;
    }
    if (s > 0) {
#pragma unroll
        for (int r = 0; r < ROWS; ++r) acc_sh[s - 1][r][j] = acc[r];
    }
    __syncthreads();
    if (s == 0) {
#pragma unroll
        for (int r = 0; r < ROWS; ++r) {
            float o = acc[r];
#pragma unroll
            for (int ss = 0; ss < SL - 1; ++ss) o += acc_sh[ss][r][j];
            C[(size_t)(i0 + r) * M + j] = o;
            GT[(size_t)j * NN + i0 + r] = (unsigned short)bfb(o);
        }
    }
}

// ---------------- el/er (multi-head), er stored transposed ert[h][i]; global er-max per head ----------------
template<int NH, int F>
__global__ void elr_kernel(const float* __restrict__ g,
                           const float* __restrict__ al,
                           const float* __restrict__ ar,
                           float* __restrict__ el, float* __restrict__ ert,
                           unsigned* __restrict__ ermax_u) {
    int t = blockIdx.x * blockDim.x + threadIdx.x; // t = i*NH + h
    int i = t / NH, h = t % NH;
    const float4* gp = (const float4*)(g + (size_t)t * F);
    const float4* alp = (const float4*)al;
    const float4* arp = (const float4*)ar;
    float sl = 0.f, sr = 0.f;
#pragma unroll
    for (int q = 0; q < F / 4; ++q) {
        float4 v = gp[q], A = alp[q], R = arp[q];
        sl += v.x * A.x + v.y * A.y + v.z * A.z + v.w * A.w;
        sr += v.x * R.x + v.y * R.y + v.z * R.z + v.w * R.w;
    }
    el[t] = sl;
    ert[(size_t)h * NN + i] = sr;

    unsigned m = fmono(sr);
    const int lane = threadIdx.x & 63;
#pragma unroll
    for (int off = 8; off <= 32; off <<= 1) {
        unsigned o = (unsigned)__shfl_xor((int)m, off);
        m = m > o ? m : o;
    }
    if (lane < 8) atomicMax(&ermax_u[lane], m); // 64%8==0 -> h == lane
}

// ---------------- el/er for single head, F=128: 4 threads per row ----------------
__global__ void elr1h_kernel(const float* __restrict__ g,
                             const float* __restrict__ al,
                             const float* __restrict__ ar,
                             float* __restrict__ el, float* __restrict__ ert,
                             unsigned* __restrict__ ermax_u) {
    int t = blockIdx.x * blockDim.x + threadIdx.x; // NN*4 threads
    int i = t >> 2, qq = t & 3;
    const float4* gp = (const float4*)(g + (size_t)i * 128 + qq * 32);
    const float4* alp = (const float4*)(al + qq * 32);
    const float4* arp = (const float4*)(ar + qq * 32);
    float sl = 0.f, sr = 0.f;
#pragma unroll
    for (int q = 0; q < 8; ++q) {
        float4 v = gp[q], A = alp[q], R = arp[q];
        sl += v.x * A.x + v.y * A.y + v.z * A.z + v.w * A.w;
        sr += v.x * R.x + v.y * R.y + v.z * R.z + v.w * R.w;
    }
    sl += __shfl_xor(sl, 1, 4); sl += __shfl_xor(sl, 2, 4);
    sr += __shfl_xor(sr, 1, 4); sr += __shfl_xor(sr, 2, 4);
    if (qq == 0) { el[i] = sl; ert[i] = sr; }
    unsigned m = fmono(sr);
#pragma unroll
    for (int off = 1; off <= 32; off <<= 1) {
        unsigned o = (unsigned)__shfl_xor((int)m, off);
        m = m > o ? m : o;
    }
    if ((threadIdx.x & 63) == 0) atomicMax(&ermax_u[0], m);
}

// ---------------- Layer-1 attention: MFMA, 16 rows x 2 heads (64 cols) per block ----------------
// 512 threads = 8 waves: wave = (jslice(2) x [head-pair 4: (hloc, nhalf)]).
// softmax shift m = lrelu(el + ermax) >= true max (lrelu monotone); masked p underflows to 0 like ref.
__global__ __launch_bounds__(512) void attn1_mfma(
        const float* __restrict__ el, const float* __restrict__ ert,
        const unsigned* __restrict__ ermax_u, const int* __restrict__ adj,
        const unsigned short* __restrict__ gbt, float* __restrict__ hb) {
    const int rt = blockIdx.x;   // 0..127 row tile
    const int sec = blockIdx.y;  // 0..3 head pair
    const int i0 = rt * 16, h0 = sec * 2, col0 = sec * 64;
    const int t = threadIdx.x;
    const int lane = t & 63, w = t >> 6;
    const int q = lane >> 4, n = lane & 15;
    // staging role
    const int slice = t >> 8, tt = t & 255;
    const int hloc = tt >> 7, m = (tt >> 3) & 15, j4 = tt & 7, joff = j4 * 4;
    // mfma role
    const int wsl = w >> 2, wl = w & 3, ahw = wl >> 1;

    __shared__ __align__(16) unsigned short pl[2][2][16][40];
    __shared__ float psum_sh[2][2][16];
    __shared__ float osh[4][16][16];

    const int h = h0 + hloc;
    const float elv = el[(size_t)(i0 + m) * 8 + h];
    float mx = lrelu(elv + fmono_inv(ermax_u[h]));
    const int* adjrow = adj + (size_t)(i0 + m) * NN + slice * 1024 + joff;
    const float* erow = ert + (size_t)h * NN + slice * 1024 + joff;
    const unsigned short* grow = gbt + (size_t)(col0 + wl * 16 + n) * NN + wsl * 1024 + q * 8;
    float ps = 0.f;
    f32x4 acc = {0.f, 0.f, 0.f, 0.f};

    for (int it = 0; it < 32; ++it) {
        const int jo = it * 32;
        int4 a4 = *(const int4*)(adjrow + jo);
        float4 e4 = *(const float4*)(erow + jo);
        float p0 = a4.x ? __expf(lrelu(elv + e4.x) - mx) : 0.f;
        float p1 = a4.y ? __expf(lrelu(elv + e4.y) - mx) : 0.f;
        float p2 = a4.z ? __expf(lrelu(elv + e4.z) - mx) : 0.f;
        float p3 = a4.w ? __expf(lrelu(elv + e4.w) - mx) : 0.f;
        ps += (p0 + p1) + (p2 + p3);
        uint2 pk;
        pk.x = bfb(p0) | (bfb(p1) << 16);
        pk.y = bfb(p2) | (bfb(p3) << 16);
        *(uint2*)&pl[slice][hloc][m][joff] = pk;
        __syncthreads();
        short8 a = *(const short8*)&pl[wsl][ahw][n][q * 8];
        short8 b = *(const short8*)(grow + jo);
        acc = __builtin_amdgcn_mfma_f32_16x16x32_bf16(a, b, acc, 0, 0, 0);
        __syncthreads();
    }
    // psum: reduce over the 8 staging threads (consecutive lanes) sharing (slice,hloc,m)
#pragma unroll
    for (int off = 4; off; off >>= 1) ps += __shfl_down(ps, off, 8);
    if (j4 == 0) psum_sh[slice][hloc][m] = ps;
    if (wsl == 1) {
#pragma unroll
        for (int r = 0; r < 4; ++r) osh[wl][q * 4 + r][n] = acc[r];
    }
    __syncthreads();
    if (wsl == 0) {
#pragma unroll
        for (int r = 0; r < 4; ++r) {
            int mr = q * 4 + r;
            float o = acc[r] + osh[wl][mr][n];
            float psv = psum_sh[0][ahw][mr] + psum_sh[1][ahw][mr];
            o /= psv;
            o = o > 0.f ? o : (__expf(o) - 1.f); // ELU
            hb[(size_t)(i0 + mr) * 256 + col0 + wl * 16 + n] = o;
        }
    }
}

// ---------------- Layer-2 attention: MFMA, 16 rows x 64 cols per block, j-half per block ----------------
__global__ __launch_bounds__(256) void attn2_mfma(
        const float* __restrict__ el, const float* __restrict__ ert,
        const unsigned* __restrict__ ermax_u, const int* __restrict__ adj,
        const unsigned short* __restrict__ gbt,
        float* __restrict__ pacc, float* __restrict__ pps) {
    const int rt = blockIdx.x;  // 0..127
    const int sec = blockIdx.y; // 0..3 = fhalf + 2*jhalf
    const int i0 = rt * 16, col0 = (sec & 1) * 64, jh = sec >> 1;
    const int jbase = jh * 1024;
    const int t = threadIdx.x;
    const int lane = t & 63, w = t >> 6;
    const int q = lane >> 4, n = lane & 15;
    const int m = t >> 4, j2 = t & 15, joff = j2 * 2;

    __shared__ __align__(16) unsigned short pl[16][40];
    __shared__ float psum_sh[16];

    const float elv = el[i0 + m];
    float mx = lrelu(elv + fmono_inv(ermax_u[0]));
    const int* adjrow = adj + (size_t)(i0 + m) * NN + jbase + joff;
    const float* erow = ert + jbase + joff;
    const unsigned short* grow = gbt + (size_t)(col0 + w * 16 + n) * NN + jbase + q * 8;
    float ps = 0.f;
    f32x4 acc = {0.f, 0.f, 0.f, 0.f};

    for (int it = 0; it < 32; ++it) {
        const int jo = it * 32;
        int2 a2 = *(const int2*)(adjrow + jo);
        float2 e2 = *(const float2*)(erow + jo);
        float p0 = a2.x ? __expf(lrelu(elv + e2.x) - mx) : 0.f;
        float p1 = a2.y ? __expf(lrelu(elv + e2.y) - mx) : 0.f;
        ps += p0 + p1;
        *(unsigned*)&pl[m][joff] = bfb(p0) | (bfb(p1) << 16);
        __syncthreads();
        short8 a = *(const short8*)&pl[n][q * 8];
        short8 b = *(const short8*)(grow + jo);
        acc = __builtin_amdgcn_mfma_f32_16x16x32_bf16(a, b, acc, 0, 0, 0);
        __syncthreads();
    }
#pragma unroll
    for (int off = 8; off; off >>= 1) ps += __shfl_down(ps, off, 16);
    if (j2 == 0) psum_sh[m] = ps;
    __syncthreads();
#pragma unroll
    for (int r = 0; r < 4; ++r) {
        int mr = q * 4 + r;
        pacc[(size_t)jh * NN * 128 + (size_t)(i0 + mr) * 128 + col0 + w * 16 + n] = acc[r];
        if (w == 0 && n == 0) pps[(size_t)jh * NN + i0 + mr] = psum_sh[mr];
    }
}

__global__ void combine2(const float* __restrict__ pacc, const float* __restrict__ pps,
                         float* __restrict__ out) {
    int idx = blockIdx.x * 256 + threadIdx.x; // < NN*128
    int i = idx >> 7;
    out[idx] = (pacc[idx] + pacc[(size_t)NN * 128 + idx]) / (pps[i] + pps[NN + i]);
}

extern "C" void kernel_launch(void* const* d_in, const int* in_sizes, int n_in,
                              void* d_out, int out_size, void* d_ws, size_t ws_size,
                              hipStream_t stream) {
    const float* x   = (const float*)d_in[0];
    const float* W1  = (const float*)d_in[1];
    const float* a1l = (const float*)d_in[2];
    const float* a1r = (const float*)d_in[3];
    const float* W2  = (const float*)d_in[4];
    const float* a2l = (const float*)d_in[5];
    const float* a2r = (const float*)d_in[6];
    const int* adj = (const int*)d_in[7];

    float* ws = (float*)d_ws;
    float* g1   = ws;                             // 2048*256 fp32
    float* hb   = g1 + (size_t)NN * 256;          // 2048*256 fp32
    float* g2   = hb + (size_t)NN * 256;          // 2048*128 fp32
    float* pacc = g2 + (size_t)NN * 128;          // 2*2048*128 fp32
    float* el1  = pacc + (size_t)2 * NN * 128;    // 2048*8
    float* ert1 = el1 + (size_t)NN * 8;           // 8*2048
    float* el2  = ert1 + (size_t)NN * 8;          // 2048
    float* ert2 = el2 + NN;                       // 2048
    float* pps  = ert2 + NN;                      // 2*2048
    unsigned short* gbt1 = (unsigned short*)(pps + 2 * NN); // 256*2048 bf16
    unsigned short* gbt2 = gbt1 + (size_t)256 * NN;         // 128*2048 bf16
    unsigned* ermax1 = (unsigned*)(gbt2 + (size_t)128 * NN); // 8
    unsigned* ermax2 = ermax1 + 8;                           // 1

    hipMemsetAsync(ermax1, 0, 9 * sizeof(unsigned), stream);

    // Layer 1
    gemm_ksplit<512, 256, 4, 4><<<NN / 4, 1024, 0, stream>>>(x, W1, g1, gbt1);
    elr_kernel<8, 32><<<(NN * 8) / 256, 256, 0, stream>>>(g1, a1l, a1r, el1, ert1, ermax1);
    attn1_mfma<<<dim3(128, 4), 512, 0, stream>>>(el1, ert1, ermax1, adj, gbt1, hb);

    // Layer 2
    gemm_ksplit<256, 128, 4, 8><<<NN / 4, 1024, 0, stream>>>(hb, W2, g2, gbt2);
    elr1h_kernel<<<(NN * 4) / 256, 256, 0, stream>>>(g2, a2l, a2r, el2, ert2, ermax2);
    attn2_mfma<<<dim3(128, 4), 256, 0, stream>>>(el2, ert2, ermax2, adj, gbt2, pacc, pps);
    combine2<<<(NN * 128) / 256, 256, 0, stream>>>(pacc, pps, (float*)d_out);
}

// Round 5
// 167.314 us; speedup vs baseline: 2.8099x; 1.0760x over previous
//
#include <hip/hip_runtime.h>
#include <hip/hip_bf16.h>

#define NN 2048
typedef unsigned short u16;
typedef __attribute__((ext_vector_type(8))) short short8;
typedef __attribute__((ext_vector_type(4))) float f32x4;

// monotone float<->uint map for atomicMax on floats (handles negatives); 0 < fmono(any finite)
__device__ __forceinline__ unsigned fmono(float x) {
    unsigned b = __float_as_uint(x);
    return (b & 0x80000000u) ? ~b : (b | 0x80000000u);
}
__device__ __forceinline__ float fmono_inv(unsigned u) {
    return (u & 0x80000000u) ? __uint_as_float(u ^ 0x80000000u) : __uint_as_float(~u);
}
// fp32 -> bf16 bits, RNE
__device__ __forceinline__ unsigned bfb(float x) {
    unsigned u = __float_as_uint(x);
    return (u + 0x7FFFu + ((u >> 16) & 1u)) >> 16;
}

// ---------------- prep: fp32 -> bf16 conversions (x, W1^T, W2^T) ----------------
__global__ __launch_bounds__(256) void prep_cvt(const float* __restrict__ x,
                                                const float* __restrict__ W1,
                                                const float* __restrict__ W2,
                                                u16* __restrict__ xb,
                                                u16* __restrict__ w1t,
                                                u16* __restrict__ w2t) {
    int t = blockIdx.x * 256 + threadIdx.x;
    if (t < 262144) {                      // x: 2048x512, float4 per thread
        float4 v = ((const float4*)x)[t];
        uint2 o;
        o.x = bfb(v.x) | (bfb(v.y) << 16);
        o.y = bfb(v.z) | (bfb(v.w) << 16);
        ((uint2*)xb)[t] = o;
    } else if (t < 262144 + 131072) {      // w1t[c][k] = W1[k][c], 256x512
        int u = t - 262144;
        int c = u >> 9, k = u & 511;
        w1t[u] = (u16)bfb(W1[(size_t)k * 256 + c]);
    } else if (t < 262144 + 131072 + 32768) { // w2t[c][k] = W2[k][c], 128x256
        int u = t - 393216;
        int c = u >> 8, k = u & 255;
        w2t[u] = (u16)bfb(W2[(size_t)k * 128 + c]);
    }
}

// ---------------- prep: adjacency bitmask ab32[i][j/32] ----------------
__global__ __launch_bounds__(256) void prep_bits(const int* __restrict__ adj,
                                                 unsigned long long* __restrict__ ab) {
    int t = blockIdx.x * 256 + threadIdx.x; // 4M threads
    int W = t >> 6, lane = t & 63;
    int i = W >> 5, jw = W & 31;
    int a = adj[(size_t)i * NN + jw * 64 + lane];
    unsigned long long m = __ballot(a != 0);
    if (lane == 0) ab[(size_t)i * 32 + jw] = m;
}

// ---------------- GEMM (bf16 MFMA, direct-from-global): C=A*BT^T; GT = bf16(C)^T ----------------
template<int K, int MOUT>
__global__ __launch_bounds__(256) void gemm_mfma(const u16* __restrict__ A,   // [rows][K]
                                                 const u16* __restrict__ BT,  // [MOUT][K]
                                                 float* __restrict__ C,       // [rows][MOUT]
                                                 u16* __restrict__ GT) {      // [MOUT][rows]
    const int i0 = blockIdx.x * 16;
    const int t = threadIdx.x, lane = t & 63, w = t >> 6;
    const int q = lane >> 4, n = lane & 15;
    const int c0 = (blockIdx.y * 4 + w) * 16;
    const u16* ap = A + (size_t)(i0 + n) * K + q * 8;
    const u16* bp = BT + (size_t)(c0 + n) * K + q * 8;
    f32x4 acc = {0.f, 0.f, 0.f, 0.f};
#pragma unroll
    for (int ks = 0; ks < K / 32; ++ks) {
        short8 a = *(const short8*)(ap + ks * 32);
        short8 b = *(const short8*)(bp + ks * 32);
        acc = __builtin_amdgcn_mfma_f32_16x16x32_bf16(a, b, acc, 0, 0, 0);
    }
    uint2 gt;
#pragma unroll
    for (int r = 0; r < 4; ++r)
        C[(size_t)(i0 + q * 4 + r) * MOUT + c0 + n] = acc[r];
    gt.x = bfb(acc[0]) | (bfb(acc[1]) << 16);
    gt.y = bfb(acc[2]) | (bfb(acc[3]) << 16);
    *(uint2*)&GT[(size_t)(c0 + n) * NN + i0 + q * 4] = gt;
}

// ---------------- el/er (8 heads, F=32) from fp32 g; ermax per head ----------------
__global__ __launch_bounds__(256) void elr8(const float* __restrict__ g,
                                            const float* __restrict__ al,
                                            const float* __restrict__ ar,
                                            float* __restrict__ el, float* __restrict__ ert,
                                            unsigned* __restrict__ ermax_u) {
    int t = blockIdx.x * 256 + threadIdx.x; // t = i*8 + h
    int i = t >> 3, h = t & 7;
    const float4* gp = (const float4*)(g + (size_t)t * 32);
    const float4* alp = (const float4*)al;
    const float4* arp = (const float4*)ar;
    float sl = 0.f, sr = 0.f;
#pragma unroll
    for (int q = 0; q < 8; ++q) {
        float4 v = gp[q], A = alp[q], R = arp[q];
        sl += v.x * A.x + v.y * A.y + v.z * A.z + v.w * A.w;
        sr += v.x * R.x + v.y * R.y + v.z * R.z + v.w * R.w;
    }
    el[t] = sl;
    ert[(size_t)h * NN + i] = sr;
    unsigned m = fmono(sr);
#pragma unroll
    for (int off = 8; off <= 32; off <<= 1) {
        unsigned o = (unsigned)__shfl_xor((int)m, off);
        m = m > o ? m : o;
    }
    if ((threadIdx.x & 63) < 8) atomicMax(&ermax_u[threadIdx.x & 7], m);
}

// ---------------- el/er (1 head, F=128): 4 threads/row ----------------
__global__ __launch_bounds__(256) void elr1(const float* __restrict__ g,
                                            const float* __restrict__ al,
                                            const float* __restrict__ ar,
                                            float* __restrict__ el, float* __restrict__ ert,
                                            unsigned* __restrict__ ermax_u) {
    int t = blockIdx.x * 256 + threadIdx.x; // NN*4 threads
    int i = t >> 2, qq = t & 3;
    const float4* gp = (const float4*)(g + (size_t)i * 128 + qq * 32);
    const float4* alp = (const float4*)(al + qq * 32);
    const float4* arp = (const float4*)(ar + qq * 32);
    float sl = 0.f, sr = 0.f;
#pragma unroll
    for (int q = 0; q < 8; ++q) {
        float4 v = gp[q], A = alp[q], R = arp[q];
        sl += v.x * A.x + v.y * A.y + v.z * A.z + v.w * A.w;
        sr += v.x * R.x + v.y * R.y + v.z * R.z + v.w * R.w;
    }
    sl += __shfl_xor(sl, 1, 4); sl += __shfl_xor(sl, 2, 4);
    sr += __shfl_xor(sr, 1, 4); sr += __shfl_xor(sr, 2, 4);
    if (qq == 0) { el[i] = sl; ert[i] = sr; }
    unsigned m = fmono(sr);
#pragma unroll
    for (int off = 1; off <= 32; off <<= 1) {
        unsigned o = (unsigned)__shfl_xor((int)m, off);
        m = m > o ? m : o;
    }
    if ((threadIdx.x & 63) == 0) atomicMax(&ermax_u[0], m);
}

// ---------------- attn1: 16 rows x all 8 heads (256 cols), j-half per block ----------------
// staging role: thread (m = t>>5, jq = t&31) -> 2 j's x 8 heads; MFMA role: wave w -> head w, 2 col-tiles
__global__ __launch_bounds__(512) void attn1(const float* __restrict__ el,    // [2048][8]
                                             const float* __restrict__ ert,   // [8][2048]
                                             const unsigned* __restrict__ ermax_u,
                                             const unsigned* __restrict__ ab32, // [2048][64]
                                             const u16* __restrict__ gbt,     // [256][2048]
                                             float* __restrict__ pacc,        // [2][2048][256]
                                             float* __restrict__ pps) {       // [2][2048][8]
    const int rt = blockIdx.x, jh = blockIdx.y;
    const int i0 = rt * 16, jbase = jh * 1024;
    const int t = threadIdx.x, lane = t & 63, w = t >> 6;
    const int q = lane >> 4, n = lane & 15;
    const int m = t >> 5, jq = t & 31;

    __shared__ __align__(16) float ers[8 * 1024];
    __shared__ __align__(16) u16 pl[8][16][72];   // [h][m][k], stride 72 shorts = 144 B
    __shared__ unsigned absh[16][32];
    __shared__ float psum_sh[16][8];

#pragma unroll
    for (int c2 = 0; c2 < 4; ++c2) {              // ers[h*1024+j] = ert[h][jbase+j]
        int L = t * 16 + c2 * 4;
        int h = L >> 10;
        *(float4*)&ers[L] = *(const float4*)(ert + (size_t)h * 1024 + jbase + L);
    }
    if (t < 512) absh[t >> 5][t & 31] = ab32[(size_t)(i0 + (t >> 5)) * 64 + jh * 32 + (t & 31)];

    float elv[8], mxv[8], ps[8];
#pragma unroll
    for (int h = 0; h < 8; ++h) {
        float e = el[(size_t)(i0 + m) * 8 + h];
        elv[h] = e;
        float mm = e + fmono_inv(ermax_u[h]);
        mxv[h] = fmaxf(mm, 0.2f * mm);
        ps[h] = 0.f;
    }
    const u16* gb0 = gbt + (size_t)(w * 32 + n) * NN + jbase + q * 8;
    const u16* gb1 = gbt + (size_t)(w * 32 + 16 + n) * NN + jbase + q * 8;
    f32x4 acc0 = {0.f, 0.f, 0.f, 0.f}, acc1 = {0.f, 0.f, 0.f, 0.f};
    __syncthreads();

    for (int tile = 0; tile < 16; ++tile) {
        const int jt = tile * 64;
        unsigned word = absh[m][tile * 2 + (jq >> 4)];
        unsigned bits = (word >> ((2 * jq) & 31)) & 3u;
        const bool b0 = bits & 1u, b1 = bits & 2u;
#pragma unroll
        for (int h = 0; h < 8; ++h) {
            float2 e2 = *(const float2*)&ers[h * 1024 + jt + 2 * jq];
            float s0 = elv[h] + e2.x, s1 = elv[h] + e2.y;
            s0 = fmaxf(s0, 0.2f * s0) - mxv[h];
            s1 = fmaxf(s1, 0.2f * s1) - mxv[h];
            float p0 = b0 ? __expf(s0) : 0.f;
            float p1 = b1 ? __expf(s1) : 0.f;
            ps[h] += p0 + p1;
            *(unsigned*)&pl[h][m][2 * jq] = bfb(p0) | (bfb(p1) << 16);
        }
        __syncthreads();
#pragma unroll
        for (int ks = 0; ks < 2; ++ks) {
            short8 a = *(const short8*)&pl[w][n][ks * 32 + q * 8];
            short8 bv0 = *(const short8*)(gb0 + jt + ks * 32);
            short8 bv1 = *(const short8*)(gb1 + jt + ks * 32);
            acc0 = __builtin_amdgcn_mfma_f32_16x16x32_bf16(a, bv0, acc0, 0, 0, 0);
            acc1 = __builtin_amdgcn_mfma_f32_16x16x32_bf16(a, bv1, acc1, 0, 0, 0);
        }
        __syncthreads();
    }

#pragma unroll
    for (int h = 0; h < 8; ++h) {
        float v = ps[h];
#pragma unroll
        for (int off = 16; off; off >>= 1) v += __shfl_down(v, off, 32);
        if (jq == 0) psum_sh[m][h] = v;
    }
    const size_t base = (size_t)jh * NN * 256;
#pragma unroll
    for (int r = 0; r < 4; ++r) {
        pacc[base + (size_t)(i0 + q * 4 + r) * 256 + w * 32 + n] = acc0[r];
        pacc[base + (size_t)(i0 + q * 4 + r) * 256 + w * 32 + 16 + n] = acc1[r];
    }
    __syncthreads();
    if (t < 128) pps[(size_t)jh * NN * 8 + (size_t)(i0 + (t >> 3)) * 8 + (t & 7)] = psum_sh[t >> 3][t & 7];
}

// ---------------- combine1: hbb = bf16(ELU((pacc0+pacc1)/psum)) ----------------
__global__ __launch_bounds__(256) void combine1(const float* __restrict__ pacc,
                                                const float* __restrict__ pps,
                                                u16* __restrict__ hbb) {
    int t = blockIdx.x * 256 + threadIdx.x; // 131072 threads x 4 elems
    int idx = t * 4;
    int i = idx >> 8, h = (idx >> 5) & 7;
    float4 a = *(const float4*)(pacc + idx);
    float4 b = *(const float4*)(pacc + (size_t)NN * 256 + idx);
    float inv = 1.f / (pps[i * 8 + h] + pps[NN * 8 + i * 8 + h]);
    float o[4] = {(a.x + b.x) * inv, (a.y + b.y) * inv, (a.z + b.z) * inv, (a.w + b.w) * inv};
#pragma unroll
    for (int k = 0; k < 4; ++k) o[k] = o[k] > 0.f ? o[k] : (__expf(o[k]) - 1.f);
    uint2 pk;
    pk.x = bfb(o[0]) | (bfb(o[1]) << 16);
    pk.y = bfb(o[2]) | (bfb(o[3]) << 16);
    *(uint2*)&hbb[idx] = pk;
}

// ---------------- attn2: 16 rows x 128 cols (1 head), j-half per block ----------------
__global__ __launch_bounds__(512) void attn2(const float* __restrict__ el,    // [2048]
                                             const float* __restrict__ ert,   // [2048]
                                             const unsigned* __restrict__ ermax_u,
                                             const unsigned* __restrict__ ab32,
                                             const u16* __restrict__ gbt,     // [128][2048]
                                             float* __restrict__ pacc,        // [2][2048][128]
                                             float* __restrict__ pps) {       // [2][2048]
    const int rt = blockIdx.x, jh = blockIdx.y;
    const int i0 = rt * 16, jbase = jh * 1024;
    const int t = threadIdx.x, lane = t & 63, w = t >> 6;
    const int q = lane >> 4, n = lane & 15;
    const int m = t >> 5, jq = t & 31;

    __shared__ __align__(16) float ers[1024];
    __shared__ __align__(16) u16 pl[16][72];
    __shared__ unsigned absh[16][32];
    __shared__ float psum_sh[16];

    if (t < 256) *(float4*)&ers[t * 4] = *(const float4*)(ert + jbase + t * 4);
    if (t < 512) absh[t >> 5][t & 31] = ab32[(size_t)(i0 + (t >> 5)) * 64 + jh * 32 + (t & 31)];

    const float elv = el[i0 + m];
    float mm = elv + fmono_inv(ermax_u[0]);
    const float mxv = fmaxf(mm, 0.2f * mm);
    const u16* gb = gbt + (size_t)(w * 16 + n) * NN + jbase + q * 8;
    f32x4 acc = {0.f, 0.f, 0.f, 0.f};
    float ps = 0.f;
    __syncthreads();

    for (int tile = 0; tile < 16; ++tile) {
        const int jt = tile * 64;
        unsigned word = absh[m][tile * 2 + (jq >> 4)];
        unsigned bits = (word >> ((2 * jq) & 31)) & 3u;
        float2 e2 = *(const float2*)&ers[jt + 2 * jq];
        float s0 = elv + e2.x, s1 = elv + e2.y;
        s0 = fmaxf(s0, 0.2f * s0) - mxv;
        s1 = fmaxf(s1, 0.2f * s1) - mxv;
        float p0 = (bits & 1u) ? __expf(s0) : 0.f;
        float p1 = (bits & 2u) ? __expf(s1) : 0.f;
        ps += p0 + p1;
        *(unsigned*)&pl[m][2 * jq] = bfb(p0) | (bfb(p1) << 16);
        __syncthreads();
#pragma unroll
        for (int ks = 0; ks < 2; ++ks) {
            short8 a = *(const short8*)&pl[n][ks * 32 + q * 8];
            short8 b = *(const short8*)(gb + jt + ks * 32);
            acc = __builtin_amdgcn_mfma_f32_16x16x32_bf16(a, b, acc, 0, 0, 0);
        }
        __syncthreads();
    }

#pragma unroll
    for (int off = 16; off; off >>= 1) ps += __shfl_down(ps, off, 32);
    if (jq == 0) psum_sh[m] = ps;
#pragma unroll
    for (int r = 0; r < 4; ++r)
        pacc[(size_t)jh * NN * 128 + (size_t)(i0 + q * 4 + r) * 128 + w * 16 + n] = acc[r];
    __syncthreads();
    if (t < 16) pps[(size_t)jh * NN + i0 + t] = psum_sh[t];
}

// ---------------- combine2: out fp32 ----------------
__global__ __launch_bounds__(256) void combine2(const float* __restrict__ pacc,
                                                const float* __restrict__ pps,
                                                float* __restrict__ out) {
    int t = blockIdx.x * 256 + threadIdx.x; // 65536 threads x 4
    int idx = t * 4;
    int i = idx >> 7;
    float4 a = *(const float4*)(pacc + idx);
    float4 b = *(const float4*)(pacc + (size_t)NN * 128 + idx);
    float inv = 1.f / (pps[i] + pps[NN + i]);
    float4 o = {(a.x + b.x) * inv, (a.y + b.y) * inv, (a.z + b.z) * inv, (a.w + b.w) * inv};
    *(float4*)(out + idx) = o;
}

extern "C" void kernel_launch(void* const* d_in, const int* in_sizes, int n_in,
                              void* d_out, int out_size, void* d_ws, size_t ws_size,
                              hipStream_t stream) {
    const float* x   = (const float*)d_in[0];
    const float* W1  = (const float*)d_in[1];
    const float* a1l = (const float*)d_in[2];
    const float* a1r = (const float*)d_in[3];
    const float* W2  = (const float*)d_in[4];
    const float* a2l = (const float*)d_in[5];
    const float* a2r = (const float*)d_in[6];
    const int* adj = (const int*)d_in[7];

    char* p = (char*)d_ws;
    u16* xb    = (u16*)p;            p += (size_t)NN * 512 * 2;
    u16* w1t   = (u16*)p;            p += (size_t)256 * 512 * 2;
    u16* w2t   = (u16*)p;            p += (size_t)128 * 256 * 2;
    unsigned* abits = (unsigned*)p;  p += (size_t)NN * 64 * 4;
    float* g1  = (float*)p;          p += (size_t)NN * 256 * 4;
    u16* gbt1  = (u16*)p;            p += (size_t)256 * NN * 2;
    float* el1 = (float*)p;          p += (size_t)NN * 8 * 4;
    float* ert1 = (float*)p;         p += (size_t)8 * NN * 4;
    float* pacc1 = (float*)p;        p += (size_t)2 * NN * 256 * 4;
    float* pps1 = (float*)p;         p += (size_t)2 * NN * 8 * 4;
    u16* hbb   = (u16*)p;            p += (size_t)NN * 256 * 2;
    float* g2  = (float*)p;          p += (size_t)NN * 128 * 4;
    u16* gbt2  = (u16*)p;            p += (size_t)128 * NN * 2;
    float* el2 = (float*)p;          p += (size_t)NN * 4;
    float* ert2 = (float*)p;         p += (size_t)NN * 4;
    float* pacc2 = (float*)p;        p += (size_t)2 * NN * 128 * 4;
    float* pps2 = (float*)p;         p += (size_t)2 * NN * 4;
    unsigned* ermax1 = (unsigned*)p; // 8
    unsigned* ermax2 = ermax1 + 8;   // 1

    hipMemsetAsync(ermax1, 0, 16 * sizeof(unsigned), stream);
    prep_cvt<<<1664, 256, 0, stream>>>(x, W1, W2, xb, w1t, w2t);
    prep_bits<<<16384, 256, 0, stream>>>(adj, (unsigned long long*)abits);

    // Layer 1
    gemm_mfma<512, 256><<<dim3(128, 4), 256, 0, stream>>>(xb, w1t, g1, gbt1);
    elr8<<<64, 256, 0, stream>>>(g1, a1l, a1r, el1, ert1, ermax1);
    attn1<<<dim3(128, 2), 512, 0, stream>>>(el1, ert1, ermax1, abits, gbt1, pacc1, pps1);
    combine1<<<512, 256, 0, stream>>>(pacc1, pps1, hbb);

    // Layer 2
    gemm_mfma<256, 128><<<dim3(128, 2), 256, 0, stream>>>(hbb, w2t, g2, gbt2);
    elr1<<<32, 256, 0, stream>>>(g2, a2l, a2r, el2, ert2, ermax2);
    attn2<<<dim3(128, 2), 512, 0, stream>>>(el2, ert2, ermax2, abits, gbt2, pacc2, pps2);
    combine2<<<256, 256, 0, stream>>>(pacc2, pps2, (float*)d_out);
}